// Round 1
// baseline (174.671 us; speedup 1.0000x reference)
//
#include <hip/hip_runtime.h>
#include <cstdint>
#include <cstddef>

typedef __attribute__((ext_vector_type(8))) short bf16x8;
typedef __attribute__((ext_vector_type(4))) float floatx4;

#define SCALE_Q 0.14433756729740643f  /* 1/sqrt(48) */

// sizes
#define BPH 128          // B*P*H = 8*4*4
#define SEQ 1024
#define DMODEL 192
#define DHEAD 48
#define DPAD 64
#define MROWS 32768      // B*P*N

__device__ __forceinline__ unsigned short f2bf(float f) {
    union { float f; unsigned int u; } v;
    v.f = f;
    unsigned int u = v.u;
    unsigned int r = u + 0x7FFFu + ((u >> 16) & 1u);
    return (unsigned short)(r >> 16);
}

// ---------------------------------------------------------------------------
// Kernel 1: QKV projection. C[m, c] = sum_k x[m,k] * w_qkv[c,k] + b_qkv[c]
// 64x64 tile per block, 4 waves x (16 rows x 64 cols) each.
// Writes q (scaled) / k to [bph][n][64] bf16 (cols 48..63 untouched garbage),
// v transposed to [bph][d][n] bf16.
// ---------------------------------------------------------------------------
__global__ __launch_bounds__(256) void qkv_kernel(
    const float* __restrict__ x,
    const float* __restrict__ w_qkv,
    const float* __restrict__ b_qkv,
    unsigned short* __restrict__ q_ws,
    unsigned short* __restrict__ k_ws,
    unsigned short* __restrict__ vt_ws)
{
    __shared__ unsigned short a_lds[64 * 200];
    __shared__ unsigned short w_lds[64 * 200];
    const int t = threadIdx.x;
    const int m0 = blockIdx.x * 64;
    const int n0 = blockIdx.y * 64;

    // stage A tile (fp32 -> bf16): 64 rows x 192 cols = 3072 float4
    #pragma unroll
    for (int i = 0; i < 12; ++i) {
        int idx = t + i * 256;
        int row = idx / 48, c4 = idx % 48;
        float4 v = *reinterpret_cast<const float4*>(x + (size_t)(m0 + row) * DMODEL + c4 * 4);
        unsigned short* dst = &a_lds[row * 200 + c4 * 4];
        dst[0] = f2bf(v.x); dst[1] = f2bf(v.y); dst[2] = f2bf(v.z); dst[3] = f2bf(v.w);
    }
    // stage W tile rows n0..n0+63
    #pragma unroll
    for (int i = 0; i < 12; ++i) {
        int idx = t + i * 256;
        int row = idx / 48, c4 = idx % 48;
        float4 v = *reinterpret_cast<const float4*>(w_qkv + (size_t)(n0 + row) * DMODEL + c4 * 4);
        unsigned short* dst = &w_lds[row * 200 + c4 * 4];
        dst[0] = f2bf(v.x); dst[1] = f2bf(v.y); dst[2] = f2bf(v.z); dst[3] = f2bf(v.w);
    }
    __syncthreads();

    const int lane = t & 63, w = t >> 6;
    const int lrow = lane & 15, lhi = lane >> 4;

    floatx4 zf = {0.f, 0.f, 0.f, 0.f};
    floatx4 acc[4] = {zf, zf, zf, zf};

    #pragma unroll
    for (int ks = 0; ks < 6; ++ks) {
        bf16x8 af = *reinterpret_cast<const bf16x8*>(&a_lds[(w * 16 + lrow) * 200 + ks * 32 + lhi * 8]);
        #pragma unroll
        for (int cb = 0; cb < 4; ++cb) {
            bf16x8 bfr = *reinterpret_cast<const bf16x8*>(&w_lds[(cb * 16 + lrow) * 200 + ks * 32 + lhi * 8]);
            acc[cb] = __builtin_amdgcn_mfma_f32_16x16x32_bf16(af, bfr, acc[cb], 0, 0, 0);
        }
    }

    const int sec = n0 / 192;  // 0=q, 1=k, 2=v (uniform per block)
    #pragma unroll
    for (int cb = 0; cb < 4; ++cb) {
        int c = n0 + cb * 16 + lrow;          // 0..575
        int cc = c - sec * 192;               // 0..191
        int h = cc / 48, dd = cc - h * 48;
        float bias = b_qkv[c];
        #pragma unroll
        for (int r = 0; r < 4; ++r) {
            int m = m0 + w * 16 + lhi * 4 + r;
            float val = acc[cb][r] + bias;
            int bp = m >> 10, n = m & 1023;
            int bph = bp * 4 + h;
            if (sec == 0) {
                q_ws[((size_t)bph * SEQ + n) * DPAD + dd] = f2bf(val * SCALE_Q);
            } else if (sec == 1) {
                k_ws[((size_t)bph * SEQ + n) * DPAD + dd] = f2bf(val);
            } else {
                vt_ws[((size_t)bph * DHEAD + dd) * SEQ + n] = f2bf(val);
            }
        }
    }
}

// ---------------------------------------------------------------------------
// Kernel 2: flash attention. One block = one (bph, 64 q-rows). 4 waves x 16 q.
// KV tiles of 64 staged in LDS. Online softmax. Output bf16 to z_ws [m][192].
// ---------------------------------------------------------------------------
__global__ __launch_bounds__(256) void attn_kernel(
    const unsigned short* __restrict__ q_ws,
    const unsigned short* __restrict__ k_ws,
    const unsigned short* __restrict__ vt_ws,
    unsigned short* __restrict__ z_ws)
{
    __shared__ unsigned short k_lds[64 * 72];
    __shared__ unsigned short vt_lds[48 * 72];
    __shared__ unsigned short p_lds[4][16 * 72];

    const int t = threadIdx.x, lane = t & 63, w = t >> 6;
    const int lrow = lane & 15, lhi = lane >> 4;
    const int bph = blockIdx.y;
    const int q0 = blockIdx.x * 64;
    const int bp = bph >> 2, h = bph & 3;

    // Q fragments (16 rows per wave, K-dim 64 with top 16 zeroed)
    const size_t qbase = ((size_t)bph * SEQ + q0 + w * 16 + lrow) * DPAD;
    bf16x8 qf0 = *reinterpret_cast<const bf16x8*>(&q_ws[qbase + lhi * 8]);
    bf16x8 qf1 = *reinterpret_cast<const bf16x8*>(&q_ws[qbase + 32 + lhi * 8]);
    bf16x8 zs = {0, 0, 0, 0, 0, 0, 0, 0};
    if (lhi >= 2) qf1 = zs;  // d = 48..63 must contribute zero

    float m_row[4] = {-INFINITY, -INFINITY, -INFINITY, -INFINITY};
    float l_row[4] = {0.f, 0.f, 0.f, 0.f};
    floatx4 zf = {0.f, 0.f, 0.f, 0.f};
    floatx4 oacc[3] = {zf, zf, zf};

    for (int kt = 0; kt < 16; ++kt) {
        const int kt0 = kt * 64;
        // stage K tile [64][64] and Vt tile [48][64]
        {
            const size_t kbase = (size_t)bph * SEQ + kt0;
            for (int i = t; i < 512; i += 256) {
                int row = i >> 3, c8 = i & 7;
                *reinterpret_cast<bf16x8*>(&k_lds[row * 72 + c8 * 8]) =
                    *reinterpret_cast<const bf16x8*>(&k_ws[(kbase + row) * DPAD + c8 * 8]);
            }
            for (int i = t; i < 384; i += 256) {
                int row = i >> 3, c8 = i & 7;
                *reinterpret_cast<bf16x8*>(&vt_lds[row * 72 + c8 * 8]) =
                    *reinterpret_cast<const bf16x8*>(&vt_ws[((size_t)bph * DHEAD + row) * SEQ + kt0 + c8 * 8]);
            }
        }
        __syncthreads();

        // S = Q K^T : rows = q (this wave's 16), cols = kv (4 blocks of 16)
        floatx4 sacc[4] = {zf, zf, zf, zf};
        #pragma unroll
        for (int kb = 0; kb < 4; ++kb) {
            bf16x8 kf0 = *reinterpret_cast<const bf16x8*>(&k_lds[(kb * 16 + lrow) * 72 + lhi * 8]);
            sacc[kb] = __builtin_amdgcn_mfma_f32_16x16x32_bf16(qf0, kf0, sacc[kb], 0, 0, 0);
            bf16x8 kf1 = *reinterpret_cast<const bf16x8*>(&k_lds[(kb * 16 + lrow) * 72 + 32 + lhi * 8]);
            sacc[kb] = __builtin_amdgcn_mfma_f32_16x16x32_bf16(qf1, kf1, sacc[kb], 0, 0, 0);
        }

        // online softmax (rows lhi*4+r live in this lane; cols across 16 lanes)
        float p[4][4];
        #pragma unroll
        for (int r = 0; r < 4; ++r) {
            float tmax = fmaxf(fmaxf(sacc[0][r], sacc[1][r]), fmaxf(sacc[2][r], sacc[3][r]));
            #pragma unroll
            for (int ms = 1; ms <= 8; ms <<= 1) tmax = fmaxf(tmax, __shfl_xor(tmax, ms, 64));
            float mnew = fmaxf(m_row[r], tmax);
            float scale = __expf(m_row[r] - mnew);
            float ts = 0.f;
            #pragma unroll
            for (int kb = 0; kb < 4; ++kb) { p[kb][r] = __expf(sacc[kb][r] - mnew); ts += p[kb][r]; }
            #pragma unroll
            for (int ms = 1; ms <= 8; ms <<= 1) ts += __shfl_xor(ts, ms, 64);
            l_row[r] = l_row[r] * scale + ts;
            m_row[r] = mnew;
            #pragma unroll
            for (int cb = 0; cb < 3; ++cb) oacc[cb][r] *= scale;
        }

        // transpose P into MFMA-A layout via per-wave LDS
        #pragma unroll
        for (int kb = 0; kb < 4; ++kb)
            #pragma unroll
            for (int r = 0; r < 4; ++r)
                p_lds[w][(lhi * 4 + r) * 72 + kb * 16 + lrow] = f2bf(p[kb][r]);
        __syncthreads();

        // O += P V : A = P [16 x 64], B = Vt cols (3 blocks of 16 d)
        #pragma unroll
        for (int ks = 0; ks < 2; ++ks) {
            bf16x8 pa = *reinterpret_cast<const bf16x8*>(&p_lds[w][lrow * 72 + ks * 32 + lhi * 8]);
            #pragma unroll
            for (int cb = 0; cb < 3; ++cb) {
                bf16x8 vf = *reinterpret_cast<const bf16x8*>(&vt_lds[(cb * 16 + lrow) * 72 + ks * 32 + lhi * 8]);
                oacc[cb] = __builtin_amdgcn_mfma_f32_16x16x32_bf16(pa, vf, oacc[cb], 0, 0, 0);
            }
        }
        __syncthreads();
    }

    // normalize and write z (merged-head layout [m][192] bf16)
    #pragma unroll
    for (int r = 0; r < 4; ++r) {
        int n = q0 + w * 16 + lhi * 4 + r;
        float inv = 1.0f / l_row[r];
        size_t zrow = ((size_t)bp * SEQ + n) * DMODEL + h * DHEAD;
        #pragma unroll
        for (int cb = 0; cb < 3; ++cb)
            z_ws[zrow + cb * 16 + lrow] = f2bf(oacc[cb][r] * inv);
    }
}

// ---------------------------------------------------------------------------
// Kernel 3: output projection. out[m, c] = sum_k z[m,k] * w_proj[c,k] + b_proj[c]
// ---------------------------------------------------------------------------
__global__ __launch_bounds__(256) void proj_kernel(
    const unsigned short* __restrict__ z_ws,
    const float* __restrict__ w_proj,
    const float* __restrict__ b_proj,
    float* __restrict__ out)
{
    __shared__ unsigned short a_lds[64 * 200];
    __shared__ unsigned short w_lds[64 * 200];
    const int t = threadIdx.x;
    const int m0 = blockIdx.x * 64;
    const int n0 = blockIdx.y * 64;

    // stage A (already bf16): 64 rows x 24 x (8 ushorts)
    for (int i = t; i < 1536; i += 256) {
        int row = i / 24, c8 = i % 24;
        *reinterpret_cast<bf16x8*>(&a_lds[row * 200 + c8 * 8]) =
            *reinterpret_cast<const bf16x8*>(&z_ws[(size_t)(m0 + row) * DMODEL + c8 * 8]);
    }
    #pragma unroll
    for (int i = 0; i < 12; ++i) {
        int idx = t + i * 256;
        int row = idx / 48, c4 = idx % 48;
        float4 v = *reinterpret_cast<const float4*>(w_proj + (size_t)(n0 + row) * DMODEL + c4 * 4);
        unsigned short* dst = &w_lds[row * 200 + c4 * 4];
        dst[0] = f2bf(v.x); dst[1] = f2bf(v.y); dst[2] = f2bf(v.z); dst[3] = f2bf(v.w);
    }
    __syncthreads();

    const int lane = t & 63, w = t >> 6;
    const int lrow = lane & 15, lhi = lane >> 4;

    floatx4 zf = {0.f, 0.f, 0.f, 0.f};
    floatx4 acc[4] = {zf, zf, zf, zf};

    #pragma unroll
    for (int ks = 0; ks < 6; ++ks) {
        bf16x8 af = *reinterpret_cast<const bf16x8*>(&a_lds[(w * 16 + lrow) * 200 + ks * 32 + lhi * 8]);
        #pragma unroll
        for (int cb = 0; cb < 4; ++cb) {
            bf16x8 bfr = *reinterpret_cast<const bf16x8*>(&w_lds[(cb * 16 + lrow) * 200 + ks * 32 + lhi * 8]);
            acc[cb] = __builtin_amdgcn_mfma_f32_16x16x32_bf16(af, bfr, acc[cb], 0, 0, 0);
        }
    }

    #pragma unroll
    for (int cb = 0; cb < 4; ++cb) {
        int c = n0 + cb * 16 + lrow;
        float bias = b_proj[c];
        #pragma unroll
        for (int r = 0; r < 4; ++r) {
            int m = m0 + w * 16 + lhi * 4 + r;
            out[(size_t)m * DMODEL + c] = acc[cb][r] + bias;
        }
    }
}

// ---------------------------------------------------------------------------
extern "C" void kernel_launch(void* const* d_in, const int* in_sizes, int n_in,
                              void* d_out, int out_size, void* d_ws, size_t ws_size,
                              hipStream_t stream) {
    const float* x      = (const float*)d_in[0];
    const float* w_qkv  = (const float*)d_in[1];
    const float* b_qkv  = (const float*)d_in[2];
    const float* w_proj = (const float*)d_in[3];
    const float* b_proj = (const float*)d_in[4];
    float* out = (float*)d_out;

    unsigned short* q_ws  = (unsigned short*)d_ws;
    unsigned short* k_ws  = q_ws + (size_t)BPH * SEQ * DPAD;            // +16.78MB
    unsigned short* vt_ws = k_ws + (size_t)BPH * SEQ * DPAD;            // +16.78MB
    unsigned short* z_ws  = vt_ws + (size_t)BPH * DHEAD * SEQ;          // +12.58MB
    // total ws usage: 58,720,256 bytes

    qkv_kernel<<<dim3(512, 9), 256, 0, stream>>>(x, w_qkv, b_qkv, q_ws, k_ws, vt_ws);
    attn_kernel<<<dim3(16, 128), 256, 0, stream>>>(q_ws, k_ws, vt_ws, z_ws);
    proj_kernel<<<dim3(512, 3), 256, 0, stream>>>(z_ws, w_proj, b_proj, out);
}

// Round 2
// 157.902 us; speedup vs baseline: 1.1062x; 1.1062x over previous
//
#include <hip/hip_runtime.h>
#include <hip/hip_bf16.h>
#include <cstdint>
#include <cstddef>

typedef __attribute__((ext_vector_type(8))) short bf16x8;
typedef __attribute__((ext_vector_type(4))) float floatx4;
typedef __attribute__((ext_vector_type(16))) float floatx16;

#define SCALE_L2E 0.20823560929138437f  /* (1/sqrt(48)) * log2(e) */

#define BPH 128          // B*P*H = 8*4*4
#define SEQ 1024
#define DMODEL 192
#define DHEAD 48
#define MROWS 32768      // B*P*N

#define ZERO16 {0.f,0.f,0.f,0.f,0.f,0.f,0.f,0.f,0.f,0.f,0.f,0.f,0.f,0.f,0.f,0.f}

__device__ __forceinline__ unsigned short bfu(float f) {
    return __bfloat16_as_ushort(__float2bfloat16(f));
}
__device__ __forceinline__ unsigned pk2(float lo, float hi) {
    return (unsigned)bfu(lo) | ((unsigned)bfu(hi) << 16);
}

// ---------------------------------------------------------------------------
// Kernel 1: QKV projection. C[m, c] = sum_k x[m,k] * w_qkv[c,k] + b_qkv[c]
// 64x64 tile per block, 4 waves x (16 rows x 64 cols) each.
// q (scaled by SCALE*log2e) / k -> [bph][n][48] bf16 ; v -> [bph][d][n] bf16.
// ---------------------------------------------------------------------------
__global__ __launch_bounds__(256) void qkv_kernel(
    const float* __restrict__ x,
    const float* __restrict__ w_qkv,
    const float* __restrict__ b_qkv,
    unsigned short* __restrict__ q_ws,
    unsigned short* __restrict__ k_ws,
    unsigned short* __restrict__ vt_ws)
{
    __shared__ unsigned short a_lds[64 * 200];
    __shared__ unsigned short w_lds[64 * 200];
    const int t = threadIdx.x;
    const int m0 = blockIdx.x * 64;
    const int n0 = blockIdx.y * 64;

    // stage A tile (fp32 -> bf16): 64 rows x 192 cols = 3072 float4
    #pragma unroll
    for (int i = 0; i < 12; ++i) {
        int idx = t + i * 256;
        int row = idx / 48, c4 = idx % 48;
        float4 v = *reinterpret_cast<const float4*>(x + (size_t)(m0 + row) * DMODEL + c4 * 4);
        unsigned short* dst = &a_lds[row * 200 + c4 * 4];
        dst[0] = bfu(v.x); dst[1] = bfu(v.y); dst[2] = bfu(v.z); dst[3] = bfu(v.w);
    }
    #pragma unroll
    for (int i = 0; i < 12; ++i) {
        int idx = t + i * 256;
        int row = idx / 48, c4 = idx % 48;
        float4 v = *reinterpret_cast<const float4*>(w_qkv + (size_t)(n0 + row) * DMODEL + c4 * 4);
        unsigned short* dst = &w_lds[row * 200 + c4 * 4];
        dst[0] = bfu(v.x); dst[1] = bfu(v.y); dst[2] = bfu(v.z); dst[3] = bfu(v.w);
    }
    __syncthreads();

    const int lane = t & 63, w = t >> 6;
    const int lrow = lane & 15, lhi = lane >> 4;

    floatx4 zf = {0.f, 0.f, 0.f, 0.f};
    floatx4 acc[4] = {zf, zf, zf, zf};

    #pragma unroll
    for (int ks = 0; ks < 6; ++ks) {
        bf16x8 af = *reinterpret_cast<const bf16x8*>(&a_lds[(w * 16 + lrow) * 200 + ks * 32 + lhi * 8]);
        #pragma unroll
        for (int cb = 0; cb < 4; ++cb) {
            bf16x8 bfr = *reinterpret_cast<const bf16x8*>(&w_lds[(cb * 16 + lrow) * 200 + ks * 32 + lhi * 8]);
            acc[cb] = __builtin_amdgcn_mfma_f32_16x16x32_bf16(af, bfr, acc[cb], 0, 0, 0);
        }
    }

    const int sec = n0 / 192;  // 0=q, 1=k, 2=v (uniform per block)
    #pragma unroll
    for (int cb = 0; cb < 4; ++cb) {
        int c = n0 + cb * 16 + lrow;          // 0..575
        int cc = c - sec * 192;               // 0..191
        int h = cc / 48, dd = cc - h * 48;
        float bias = b_qkv[c];
        #pragma unroll
        for (int r = 0; r < 4; ++r) {
            int m = m0 + w * 16 + lhi * 4 + r;
            float val = acc[cb][r] + bias;
            int bp = m >> 10, n = m & 1023;
            int bph = bp * 4 + h;
            if (sec == 0) {
                q_ws[((size_t)bph * SEQ + n) * DHEAD + dd] = bfu(val * SCALE_L2E);
            } else if (sec == 1) {
                k_ws[((size_t)bph * SEQ + n) * DHEAD + dd] = bfu(val);
            } else {
                vt_ws[((size_t)bph * DHEAD + dd) * SEQ + n] = bfu(val);
            }
        }
    }
}

// ---------------------------------------------------------------------------
// Kernel 2: flash attention, swapped-operand 32x32x16 MFMA, no LDS.
// One wave = 32 q rows of one (b,p,h). Block = 4 waves (same bph).
// S^T = mfma(K, Q^T): lane holds P[q=lane&31][32 kv values] -> in-register
// softmax (1 shfl per reduction) -> pack bf16 + shfl_xor(32) redistribution
// -> O^T = mfma(Vt, P^T). K/V read directly through L1/L2 (fits cache).
// ---------------------------------------------------------------------------
__global__ __launch_bounds__(256) void attn_kernel(
    const unsigned short* __restrict__ q_ws,
    const unsigned short* __restrict__ k_ws,
    const unsigned short* __restrict__ vt_ws,
    unsigned short* __restrict__ z_ws)
{
    const int t = threadIdx.x, lane = t & 63, w = t >> 6;
    const int q31 = lane & 31, hi = lane >> 5;
    const int bph = blockIdx.y;
    const int q0 = blockIdx.x * 128 + w * 32;
    const int bp = bph >> 2, h = bph & 3;

    // Q fragments (3 k-slices of 16), pre-scaled by SCALE*log2e
    bf16x8 qf[3];
    {
        const unsigned short* qp = q_ws + ((size_t)bph * SEQ + q0 + q31) * DHEAD + hi * 8;
        #pragma unroll
        for (int ks = 0; ks < 3; ++ks)
            qf[ks] = *reinterpret_cast<const bf16x8*>(qp + ks * 16);
    }

    // per-lane row pointers (lane&31 selects the kv row / d row)
    const unsigned short* kp  = k_ws + ((size_t)bph * SEQ + q31) * DHEAD + hi * 8;
    const int vrow1 = (32 + q31 > 47) ? 47 : (32 + q31);   // d rows 48..63 -> dup row 47, outputs discarded
    const unsigned short* vp0 = vt_ws + ((size_t)bph * DHEAD + q31)  * (size_t)SEQ + hi * 8;
    const unsigned short* vp1 = vt_ws + ((size_t)bph * DHEAD + vrow1) * (size_t)SEQ + hi * 8;

    floatx16 oa0 = ZERO16, oa1 = ZERO16;
    float m_prev = -INFINITY, l_sum = 0.f;

    #pragma unroll 1
    for (int kt = 0; kt < 16; ++kt) {
        const int kt0 = kt * 64;

        // ---- S^T = K . Q^T  (2 kv-blocks of 32) ----
        floatx16 s0 = ZERO16, s1 = ZERO16;
        const unsigned short* kpt = kp + (size_t)kt0 * DHEAD;
        #pragma unroll
        for (int ks = 0; ks < 3; ++ks) {
            bf16x8 kf0 = *reinterpret_cast<const bf16x8*>(kpt + ks * 16);
            bf16x8 kf1 = *reinterpret_cast<const bf16x8*>(kpt + 32 * DHEAD + ks * 16);
            s0 = __builtin_amdgcn_mfma_f32_32x32x16_bf16(kf0, qf[ks], s0, 0, 0, 0);
            s1 = __builtin_amdgcn_mfma_f32_32x32x16_bf16(kf1, qf[ks], s1, 0, 0, 0);
        }

        // ---- online softmax: lane owns half the row; partner is lane^32 ----
        float tmax = fmaxf(s0[0], s1[0]);
        #pragma unroll
        for (int r = 1; r < 16; ++r) tmax = fmaxf(tmax, fmaxf(s0[r], s1[r]));
        tmax = fmaxf(tmax, __shfl_xor(tmax, 32, 64));
        const float mnew = fmaxf(m_prev, tmax);
        const float scale = exp2f(m_prev - mnew);
        m_prev = mnew;
        oa0 = oa0 * scale;
        oa1 = oa1 * scale;

        float ts = 0.f;
        #pragma unroll
        for (int kvb = 0; kvb < 2; ++kvb) {
            // exp + pack to bf16 pairs; X = partner lane's words
            unsigned W[8], X[8];
            #pragma unroll
            for (int u = 0; u < 8; ++u) {
                float e0 = exp2f((kvb ? s1[2*u]   : s0[2*u])   - mnew);
                float e1 = exp2f((kvb ? s1[2*u+1] : s0[2*u+1]) - mnew);
                ts += e0 + e1;
                W[u] = pk2(e0, e1);
                X[u] = __shfl_xor(W[u], 32, 64);
            }
            // ---- O^T += Vt . P^T ----
            #pragma unroll
            for (int s = 0; s < 2; ++s) {
                const int a = s * 4;
                union { bf16x8 v; unsigned wd[4]; } pf;
                pf.wd[0] = hi ? X[a+2] : W[a];
                pf.wd[1] = hi ? X[a+3] : W[a+1];
                pf.wd[2] = hi ? W[a+2] : X[a];
                pf.wd[3] = hi ? W[a+3] : X[a+1];
                const int ksv = kvb * 2 + s;
                bf16x8 vf0 = *reinterpret_cast<const bf16x8*>(vp0 + kt0 + ksv * 16);
                bf16x8 vf1 = *reinterpret_cast<const bf16x8*>(vp1 + kt0 + ksv * 16);
                oa0 = __builtin_amdgcn_mfma_f32_32x32x16_bf16(vf0, pf.v, oa0, 0, 0, 0);
                oa1 = __builtin_amdgcn_mfma_f32_32x32x16_bf16(vf1, pf.v, oa1, 0, 0, 0);
            }
        }
        ts += __shfl_xor(ts, 32, 64);
        l_sum = l_sum * scale + ts;
    }

    // ---- normalize + write z [bp][n][192] bf16 (paired u32 stores) ----
    const float inv = 1.0f / l_sum;
    unsigned* zp = reinterpret_cast<unsigned*>(
        z_ws + ((size_t)bp * SEQ + q0 + q31) * DMODEL + h * DHEAD);
    #pragma unroll
    for (int u = 0; u < 8; ++u) {
        int d = 2 * (u & 1) + 8 * (u >> 1) + 4 * hi;       // d, d+1
        zp[d >> 1] = pk2(oa0[2*u] * inv, oa0[2*u+1] * inv);
    }
    #pragma unroll
    for (int u = 0; u < 4; ++u) {
        int d = 32 + 2 * (u & 1) + 8 * (u >> 1) + 4 * hi;  // 32..47 only
        zp[d >> 1] = pk2(oa1[2*u] * inv, oa1[2*u+1] * inv);
    }
}

// ---------------------------------------------------------------------------
// Kernel 3: output projection. out[m, c] = sum_k z[m,k] * w_proj[c,k] + b_proj[c]
// ---------------------------------------------------------------------------
__global__ __launch_bounds__(256) void proj_kernel(
    const unsigned short* __restrict__ z_ws,
    const float* __restrict__ w_proj,
    const float* __restrict__ b_proj,
    float* __restrict__ out)
{
    __shared__ unsigned short a_lds[64 * 200];
    __shared__ unsigned short w_lds[64 * 200];
    const int t = threadIdx.x;
    const int m0 = blockIdx.x * 64;
    const int n0 = blockIdx.y * 64;

    for (int i = t; i < 1536; i += 256) {
        int row = i / 24, c8 = i % 24;
        *reinterpret_cast<bf16x8*>(&a_lds[row * 200 + c8 * 8]) =
            *reinterpret_cast<const bf16x8*>(&z_ws[(size_t)(m0 + row) * DMODEL + c8 * 8]);
    }
    #pragma unroll
    for (int i = 0; i < 12; ++i) {
        int idx = t + i * 256;
        int row = idx / 48, c4 = idx % 48;
        float4 v = *reinterpret_cast<const float4*>(w_proj + (size_t)(n0 + row) * DMODEL + c4 * 4);
        unsigned short* dst = &w_lds[row * 200 + c4 * 4];
        dst[0] = bfu(v.x); dst[1] = bfu(v.y); dst[2] = bfu(v.z); dst[3] = bfu(v.w);
    }
    __syncthreads();

    const int lane = t & 63, w = t >> 6;
    const int lrow = lane & 15, lhi = lane >> 4;

    floatx4 zf = {0.f, 0.f, 0.f, 0.f};
    floatx4 acc[4] = {zf, zf, zf, zf};

    #pragma unroll
    for (int ks = 0; ks < 6; ++ks) {
        bf16x8 af = *reinterpret_cast<const bf16x8*>(&a_lds[(w * 16 + lrow) * 200 + ks * 32 + lhi * 8]);
        #pragma unroll
        for (int cb = 0; cb < 4; ++cb) {
            bf16x8 bfr = *reinterpret_cast<const bf16x8*>(&w_lds[(cb * 16 + lrow) * 200 + ks * 32 + lhi * 8]);
            acc[cb] = __builtin_amdgcn_mfma_f32_16x16x32_bf16(af, bfr, acc[cb], 0, 0, 0);
        }
    }

    #pragma unroll
    for (int cb = 0; cb < 4; ++cb) {
        int c = n0 + cb * 16 + lrow;
        float bias = b_proj[c];
        #pragma unroll
        for (int r = 0; r < 4; ++r) {
            int m = m0 + w * 16 + lhi * 4 + r;
            out[(size_t)m * DMODEL + c] = acc[cb][r] + bias;
        }
    }
}

// ---------------------------------------------------------------------------
extern "C" void kernel_launch(void* const* d_in, const int* in_sizes, int n_in,
                              void* d_out, int out_size, void* d_ws, size_t ws_size,
                              hipStream_t stream) {
    const float* x      = (const float*)d_in[0];
    const float* w_qkv  = (const float*)d_in[1];
    const float* b_qkv  = (const float*)d_in[2];
    const float* w_proj = (const float*)d_in[3];
    const float* b_proj = (const float*)d_in[4];
    float* out = (float*)d_out;

    unsigned short* q_ws  = (unsigned short*)d_ws;
    unsigned short* k_ws  = q_ws  + (size_t)BPH * SEQ * DHEAD;   // 6.29M elems each
    unsigned short* vt_ws = k_ws  + (size_t)BPH * SEQ * DHEAD;
    unsigned short* z_ws  = vt_ws + (size_t)BPH * DHEAD * SEQ;
    // total ws usage: 4 * 12.58 MB = 50.3 MB

    qkv_kernel<<<dim3(512, 9), 256, 0, stream>>>(x, w_qkv, b_qkv, q_ws, k_ws, vt_ws);
    attn_kernel<<<dim3(8, 128), 256, 0, stream>>>(q_ws, k_ws, vt_ws, z_ws);
    proj_kernel<<<dim3(512, 3), 256, 0, stream>>>(z_ws, w_proj, b_proj, out);
}

// Round 3
// 111.071 us; speedup vs baseline: 1.5726x; 1.4216x over previous
//
#include <hip/hip_runtime.h>
#include <hip/hip_bf16.h>
#include <cstdint>
#include <cstddef>

typedef __attribute__((ext_vector_type(8))) short bf16x8;
typedef __attribute__((ext_vector_type(4))) float floatx4;
typedef __attribute__((ext_vector_type(16))) float floatx16;

#define SCALE_L2E 0.20823560929138437f  /* (1/sqrt(48)) * log2(e) */

#define BPH 128          // B*P*H = 8*4*4
#define SEQ 1024
#define DMODEL 192
#define DHEAD 48
#define MROWS 32768      // B*P*N
#define RESCALE_THR 11.5f  /* log2 domain ~ e^8 */

#define ZERO16 {0.f,0.f,0.f,0.f,0.f,0.f,0.f,0.f,0.f,0.f,0.f,0.f,0.f,0.f,0.f,0.f}

__device__ __forceinline__ unsigned short bfu(float f) {
    return __bfloat16_as_ushort(__float2bfloat16(f));
}
__device__ __forceinline__ unsigned pk2(float lo, float hi) {
    return (unsigned)bfu(lo) | ((unsigned)bfu(hi) << 16);
}

// ---------------------------------------------------------------------------
// Kernel 1: QKV projection. C[m, c] = sum_k x[m,k] * w_qkv[c,k] + b_qkv[c]
// 64x64 tile per block, 4 waves x (16 rows x 64 cols) each.
// q (scaled by SCALE*log2e) / k -> [bph][n][48] bf16.
// v -> [bph][d][n] bf16, transposed through LDS for coalesced stores.
// ---------------------------------------------------------------------------
__global__ __launch_bounds__(256) void qkv_kernel(
    const float* __restrict__ x,
    const float* __restrict__ w_qkv,
    const float* __restrict__ b_qkv,
    unsigned short* __restrict__ q_ws,
    unsigned short* __restrict__ k_ws,
    unsigned short* __restrict__ vt_ws)
{
    __shared__ unsigned short a_lds[64 * 200];
    __shared__ unsigned short w_lds[64 * 200];
    const int t = threadIdx.x;
    const int m0 = blockIdx.x * 64;
    const int n0 = blockIdx.y * 64;

    // stage A tile (fp32 -> bf16): 64 rows x 192 cols = 3072 float4
    #pragma unroll
    for (int i = 0; i < 12; ++i) {
        int idx = t + i * 256;
        int row = idx / 48, c4 = idx % 48;
        float4 v = *reinterpret_cast<const float4*>(x + (size_t)(m0 + row) * DMODEL + c4 * 4);
        unsigned short* dst = &a_lds[row * 200 + c4 * 4];
        dst[0] = bfu(v.x); dst[1] = bfu(v.y); dst[2] = bfu(v.z); dst[3] = bfu(v.w);
    }
    #pragma unroll
    for (int i = 0; i < 12; ++i) {
        int idx = t + i * 256;
        int row = idx / 48, c4 = idx % 48;
        float4 v = *reinterpret_cast<const float4*>(w_qkv + (size_t)(n0 + row) * DMODEL + c4 * 4);
        unsigned short* dst = &w_lds[row * 200 + c4 * 4];
        dst[0] = bfu(v.x); dst[1] = bfu(v.y); dst[2] = bfu(v.z); dst[3] = bfu(v.w);
    }
    __syncthreads();

    const int lane = t & 63, w = t >> 6;
    const int lrow = lane & 15, lhi = lane >> 4;

    floatx4 zf = {0.f, 0.f, 0.f, 0.f};
    floatx4 acc[4] = {zf, zf, zf, zf};

    #pragma unroll
    for (int ks = 0; ks < 6; ++ks) {
        bf16x8 af = *reinterpret_cast<const bf16x8*>(&a_lds[(w * 16 + lrow) * 200 + ks * 32 + lhi * 8]);
        #pragma unroll
        for (int cb = 0; cb < 4; ++cb) {
            bf16x8 bfr = *reinterpret_cast<const bf16x8*>(&w_lds[(cb * 16 + lrow) * 200 + ks * 32 + lhi * 8]);
            acc[cb] = __builtin_amdgcn_mfma_f32_16x16x32_bf16(af, bfr, acc[cb], 0, 0, 0);
        }
    }

    const int sec = n0 / 192;  // 0=q, 1=k, 2=v (uniform per block)
    if (sec == 2) {
        // V: transpose through LDS -> coalesced [d][n] stores
        __syncthreads();  // a_lds reads done; reuse as [64 c][72 pad] tile
        #pragma unroll
        for (int cb = 0; cb < 4; ++cb) {
            float bias = b_qkv[n0 + cb * 16 + lrow];
            #pragma unroll
            for (int r = 0; r < 4; ++r)
                a_lds[(cb * 16 + lrow) * 72 + (w * 16 + lhi * 4 + r)] = bfu(acc[cb][r] + bias);
        }
        __syncthreads();
        const int bp = m0 >> 10, nb = m0 & 1023;
        #pragma unroll
        for (int i = 0; i < 2; ++i) {
            int ch = t + i * 256;          // 512 chunks of 8 u16
            int c_local = ch >> 3, seg = ch & 7;
            int cc = n0 + c_local - 384;   // 0..191
            int h = cc / 48, dd = cc - h * 48;
            *reinterpret_cast<bf16x8*>(
                &vt_ws[((size_t)(bp * 4 + h) * DHEAD + dd) * SEQ + nb + seg * 8]) =
                *reinterpret_cast<const bf16x8*>(&a_lds[c_local * 72 + seg * 8]);
        }
    } else {
        #pragma unroll
        for (int cb = 0; cb < 4; ++cb) {
            int c = n0 + cb * 16 + lrow;          // 0..383
            int cc = c - sec * 192;               // 0..191
            int h = cc / 48, dd = cc - h * 48;
            float bias = b_qkv[c];
            #pragma unroll
            for (int r = 0; r < 4; ++r) {
                int m = m0 + w * 16 + lhi * 4 + r;
                float val = acc[cb][r] + bias;
                int bp = m >> 10, n = m & 1023;
                int bph = bp * 4 + h;
                if (sec == 0) {
                    q_ws[((size_t)bph * SEQ + n) * DHEAD + dd] = bfu(val * SCALE_L2E);
                } else {
                    k_ws[((size_t)bph * SEQ + n) * DHEAD + dd] = bfu(val);
                }
            }
        }
    }
}

// ---------------------------------------------------------------------------
// Kernel 2: flash attention, swapped-operand 32x32x16 MFMA, no LDS.
// One wave = 32 q rows of one (b,p,h). Block = 4 waves (same bph).
// XCD-swizzled dispatch: all 8 q-blocks of a bph land on the same XCD
// (16 bph x 196KB = 3.1MB K+V per XCD L2). K+V loads issued at tile top;
// defer-max skips O-rescale when tile max doesn't grow.
// ---------------------------------------------------------------------------
__global__ __launch_bounds__(256, 4) void attn_kernel(
    const unsigned short* __restrict__ q_ws,
    const unsigned short* __restrict__ k_ws,
    const unsigned short* __restrict__ vt_ws,
    unsigned short* __restrict__ z_ws)
{
    const int t = threadIdx.x, lane = t & 63, w = t >> 6;
    const int q31 = lane & 31, hi = lane >> 5;
    // XCD swizzle: d%8 == bph%8 -> all q-chunks of a bph on one XCD
    const int d = blockIdx.x;
    const int bph = (d & 7) | ((d >> 6) << 3);
    const int qc = (d >> 3) & 7;
    const int q0 = qc * 128 + w * 32;
    const int bp = bph >> 2, h = bph & 3;

    // Q fragments (3 k-slices of 16), pre-scaled by SCALE*log2e
    bf16x8 qf[3];
    {
        const unsigned short* qp = q_ws + ((size_t)bph * SEQ + q0 + q31) * DHEAD + hi * 8;
        #pragma unroll
        for (int ks = 0; ks < 3; ++ks)
            qf[ks] = *reinterpret_cast<const bf16x8*>(qp + ks * 16);
    }

    // per-lane row pointers (lane&31 selects the kv row / d row)
    const unsigned short* kp  = k_ws + ((size_t)bph * SEQ + q31) * DHEAD + hi * 8;
    const int vrow1 = (32 + q31 > 47) ? 47 : (32 + q31);   // d rows 48..63 -> dup row 47, discarded
    const unsigned short* vp0 = vt_ws + ((size_t)bph * DHEAD + q31)  * (size_t)SEQ + hi * 8;
    const unsigned short* vp1 = vt_ws + ((size_t)bph * DHEAD + vrow1) * (size_t)SEQ + hi * 8;

    floatx16 oa0 = ZERO16, oa1 = ZERO16;
    float m_prev = -INFINITY, l_sum = 0.f;

    #pragma unroll 1
    for (int kt = 0; kt < 16; ++kt) {
        const int kt0 = kt * 64;

        // ---- issue ALL tile loads up front (V latency hides under QK^T+softmax) ----
        const unsigned short* kpt = kp + (size_t)kt0 * DHEAD;
        bf16x8 kf[6], vf0[4], vf1[4];
        #pragma unroll
        for (int ks = 0; ks < 3; ++ks) {
            kf[ks]     = *reinterpret_cast<const bf16x8*>(kpt + ks * 16);
            kf[ks + 3] = *reinterpret_cast<const bf16x8*>(kpt + 32 * DHEAD + ks * 16);
        }
        #pragma unroll
        for (int ksv = 0; ksv < 4; ++ksv) {
            vf0[ksv] = *reinterpret_cast<const bf16x8*>(vp0 + kt0 + ksv * 16);
            vf1[ksv] = *reinterpret_cast<const bf16x8*>(vp1 + kt0 + ksv * 16);
        }

        // ---- S^T = K . Q^T  (2 kv-blocks of 32) ----
        floatx16 s0 = ZERO16, s1 = ZERO16;
        #pragma unroll
        for (int ks = 0; ks < 3; ++ks) {
            s0 = __builtin_amdgcn_mfma_f32_32x32x16_bf16(kf[ks],     qf[ks], s0, 0, 0, 0);
            s1 = __builtin_amdgcn_mfma_f32_32x32x16_bf16(kf[ks + 3], qf[ks], s1, 0, 0, 0);
        }

        // ---- online softmax with defer-max ----
        float tmax = fmaxf(s0[0], s1[0]);
        #pragma unroll
        for (int r = 1; r < 16; ++r) tmax = fmaxf(tmax, fmaxf(s0[r], s1[r]));
        tmax = fmaxf(tmax, __shfl_xor(tmax, 32, 64));
        if (!__all((int)(tmax <= m_prev + RESCALE_THR))) {
            const float mnew = fmaxf(m_prev, tmax);
            const float scale = exp2f(m_prev - mnew);
            m_prev = mnew;
            l_sum *= scale;
            oa0 = oa0 * scale;
            oa1 = oa1 * scale;
        }
        const float mref = m_prev;

        float ts = 0.f;
        #pragma unroll
        for (int kvb = 0; kvb < 2; ++kvb) {
            // exp + pack to bf16 pairs; X = partner lane's words
            unsigned W[8], X[8];
            #pragma unroll
            for (int u = 0; u < 8; ++u) {
                float e0 = __builtin_amdgcn_exp2f((kvb ? s1[2*u]   : s0[2*u])   - mref);
                float e1 = __builtin_amdgcn_exp2f((kvb ? s1[2*u+1] : s0[2*u+1]) - mref);
                ts += e0 + e1;
                W[u] = pk2(e0, e1);
                X[u] = __shfl_xor(W[u], 32, 64);
            }
            // ---- O^T += Vt . P^T ----
            #pragma unroll
            for (int s = 0; s < 2; ++s) {
                const int a = s * 4;
                union { bf16x8 v; unsigned wd[4]; } pf;
                pf.wd[0] = hi ? X[a+2] : W[a];
                pf.wd[1] = hi ? X[a+3] : W[a+1];
                pf.wd[2] = hi ? W[a+2] : X[a];
                pf.wd[3] = hi ? W[a+3] : X[a+1];
                const int ksv = kvb * 2 + s;
                oa0 = __builtin_amdgcn_mfma_f32_32x32x16_bf16(vf0[ksv], pf.v, oa0, 0, 0, 0);
                oa1 = __builtin_amdgcn_mfma_f32_32x32x16_bf16(vf1[ksv], pf.v, oa1, 0, 0, 0);
            }
        }
        ts += __shfl_xor(ts, 32, 64);
        l_sum += ts;
    }

    // ---- normalize + write z [bp][n][192] bf16 (paired u32 stores) ----
    const float inv = 1.0f / l_sum;
    unsigned* zp = reinterpret_cast<unsigned*>(
        z_ws + ((size_t)bp * SEQ + q0 + q31) * DMODEL + h * DHEAD);
    #pragma unroll
    for (int u = 0; u < 8; ++u) {
        int dd = 2 * (u & 1) + 8 * (u >> 1) + 4 * hi;       // d, d+1
        zp[dd >> 1] = pk2(oa0[2*u] * inv, oa0[2*u+1] * inv);
    }
    #pragma unroll
    for (int u = 0; u < 4; ++u) {
        int dd = 32 + 2 * (u & 1) + 8 * (u >> 1) + 4 * hi;  // 32..47 only
        zp[dd >> 1] = pk2(oa1[2*u] * inv, oa1[2*u+1] * inv);
    }
}

// ---------------------------------------------------------------------------
// Kernel 3: output projection. out[m, c] = sum_k z[m,k] * w_proj[c,k] + b_proj[c]
// ---------------------------------------------------------------------------
__global__ __launch_bounds__(256) void proj_kernel(
    const unsigned short* __restrict__ z_ws,
    const float* __restrict__ w_proj,
    const float* __restrict__ b_proj,
    float* __restrict__ out)
{
    __shared__ unsigned short a_lds[64 * 200];
    __shared__ unsigned short w_lds[64 * 200];
    const int t = threadIdx.x;
    const int m0 = blockIdx.x * 64;
    const int n0 = blockIdx.y * 64;

    for (int i = t; i < 1536; i += 256) {
        int row = i / 24, c8 = i % 24;
        *reinterpret_cast<bf16x8*>(&a_lds[row * 200 + c8 * 8]) =
            *reinterpret_cast<const bf16x8*>(&z_ws[(size_t)(m0 + row) * DMODEL + c8 * 8]);
    }
    #pragma unroll
    for (int i = 0; i < 12; ++i) {
        int idx = t + i * 256;
        int row = idx / 48, c4 = idx % 48;
        float4 v = *reinterpret_cast<const float4*>(w_proj + (size_t)(n0 + row) * DMODEL + c4 * 4);
        unsigned short* dst = &w_lds[row * 200 + c4 * 4];
        dst[0] = bfu(v.x); dst[1] = bfu(v.y); dst[2] = bfu(v.z); dst[3] = bfu(v.w);
    }
    __syncthreads();

    const int lane = t & 63, w = t >> 6;
    const int lrow = lane & 15, lhi = lane >> 4;

    floatx4 zf = {0.f, 0.f, 0.f, 0.f};
    floatx4 acc[4] = {zf, zf, zf, zf};

    #pragma unroll
    for (int ks = 0; ks < 6; ++ks) {
        bf16x8 af = *reinterpret_cast<const bf16x8*>(&a_lds[(w * 16 + lrow) * 200 + ks * 32 + lhi * 8]);
        #pragma unroll
        for (int cb = 0; cb < 4; ++cb) {
            bf16x8 bfr = *reinterpret_cast<const bf16x8*>(&w_lds[(cb * 16 + lrow) * 200 + ks * 32 + lhi * 8]);
            acc[cb] = __builtin_amdgcn_mfma_f32_16x16x32_bf16(af, bfr, acc[cb], 0, 0, 0);
        }
    }

    #pragma unroll
    for (int cb = 0; cb < 4; ++cb) {
        int c = n0 + cb * 16 + lrow;
        float bias = b_proj[c];
        #pragma unroll
        for (int r = 0; r < 4; ++r) {
            int m = m0 + w * 16 + lhi * 4 + r;
            out[(size_t)m * DMODEL + c] = acc[cb][r] + bias;
        }
    }
}

// ---------------------------------------------------------------------------
extern "C" void kernel_launch(void* const* d_in, const int* in_sizes, int n_in,
                              void* d_out, int out_size, void* d_ws, size_t ws_size,
                              hipStream_t stream) {
    const float* x      = (const float*)d_in[0];
    const float* w_qkv  = (const float*)d_in[1];
    const float* b_qkv  = (const float*)d_in[2];
    const float* w_proj = (const float*)d_in[3];
    const float* b_proj = (const float*)d_in[4];
    float* out = (float*)d_out;

    unsigned short* q_ws  = (unsigned short*)d_ws;
    unsigned short* k_ws  = q_ws  + (size_t)BPH * SEQ * DHEAD;   // 6.29M elems each
    unsigned short* vt_ws = k_ws  + (size_t)BPH * SEQ * DHEAD;
    unsigned short* z_ws  = vt_ws + (size_t)BPH * DHEAD * SEQ;
    // total ws usage: 4 * 12.58 MB = 50.3 MB

    qkv_kernel<<<dim3(512, 9), 256, 0, stream>>>(x, w_qkv, b_qkv, q_ws, k_ws, vt_ws);
    attn_kernel<<<1024, 256, 0, stream>>>(q_ws, k_ws, vt_ws, z_ws);
    proj_kernel<<<dim3(512, 3), 256, 0, stream>>>(z_ws, w_proj, b_proj, out);
}